// Round 4
// baseline (3619.522 us; speedup 1.0000x reference)
//
#include <hip/hip_runtime.h>
#include <cstdint>
#include <cstddef>

#define BATCH   4
#define NPTS    16384
#define NPOINT  1024
#define NSAMPLE 32
#define CIN     67          // 3 + 64 feature channels
#define R2f     0.04f       // (float)(0.2*0.2)

// ---- multi-block FPS geometry ----
#define FPS_KB  8           // blocks per batch
#define FPS_T   512         // threads per block (8 waves)
#define FPS_P   4           // 16384 / (FPS_KB*FPS_T) points per thread

#define RPT4(M)  M(0)M(1)M(2)M(3)
#define RPT16(M) M(0)M(1)M(2)M(3)M(4)M(5)M(6)M(7)M(8)M(9)M(10)M(11)M(12)M(13)M(14)M(15)

// ---------------------------------------------------------------------------
// DPP-based argmax combine: max value, tie -> lowest index. VALU-pipe only.
// ---------------------------------------------------------------------------
template <int CTRL, int RMASK>
__device__ __forceinline__ void amax_dpp(float& v, int& i) {
  int nv = __builtin_amdgcn_update_dpp(__float_as_int(v), __float_as_int(v),
                                       CTRL, RMASK, 0xf, false);
  int ni = __builtin_amdgcn_update_dpp(i, i, CTRL, RMASK, 0xf, false);
  float fv = __int_as_float(nv);
  bool tk = (fv > v) || (fv == v && ni < i);
  v = tk ? fv : v;
  i = tk ? ni : i;
}

// ---------------------------------------------------------------------------
// Multi-block FPS. R3 post-mortem: single-block FPS is VALU-issue-bound on
// 4 CUs (VALUBusy = 85% of the 4-CU ceiling; FETCH_SIZE was KB not MB -- no
// HBM problem exists). Fix: 8 blocks/batch (32 CUs), 4 pts/thread in regs.
// Cross-block combine per iteration via device-scope atomicMax on a packed
// key + monotone-counter spin barrier:
//   key = (it+1)<<46 | dd_bits<<14 | (16383-idx)
//   - iteration tag: stale keys (earlier it) always lose the max
//   - ping-pong slot by it&1: a laggard block must read iter-it's slot
//     before any block can arrive at iter it+2 (counter gates), so the
//     other-parity slot is never overwritten under a reader
//   - inv_idx: max-key => lowest global index on value ties (ref argmax)
// Counter is monotone (target = 8*(it+1)): no reset race. Region zeroed by
// hipMemsetAsync each launch. 32 blocks <= 256 CUs: co-resident, no deadlock.
// ---------------------------------------------------------------------------
__global__ void __launch_bounds__(FPS_T)
fps_multi(const float* __restrict__ xyz, float* __restrict__ out_newxyz,
          unsigned long long* __restrict__ skey,   // [BATCH][2] ping-pong
          unsigned int* __restrict__ scnt)         // [BATCH] monotone counter
{
  const int b   = blockIdx.x >> 3;                 // batch
  const int blk = blockIdx.x & 7;                  // block within batch
  const float* base = xyz + (size_t)b * NPTS * 3;
  const int t = threadIdx.x;
  const int lane = t & 63, w = t >> 6;             // w in 0..7

  // this block's chunk: global idx = (blk<<11) + (i<<9) + t
#define DECLV(i) float px##i, py##i, pz##i, dd##i;
  RPT4(DECLV)
#undef DECLV
#define LOADV(i) { const float* p = base + (size_t)((blk << 11) + ((i) << 9) + t) * 3; \
                   px##i = p[0]; py##i = p[1]; pz##i = p[2]; dd##i = 1e10f; }
  RPT4(LOADV)
#undef LOADV

  __shared__ float s_wv[2][8];
  __shared__ int   s_wi[2][8];
  __shared__ int   s_far;

  float cx = base[0], cy = base[1], cz = base[2];

  for (int it = 0; it < NPOINT; ++it) {
    if (blk == 0 && t == 0) {           // record centroid (pre-update far)
      int o = (b * NPOINT + it) * 3;
      out_newxyz[o + 0] = cx;
      out_newxyz[o + 1] = cy;
      out_newxyz[o + 2] = cz;
    }
    float bv = -1.0f; int bl = 0;
    // exactness: keep XLA's (dx*dx + dy*dy) + dz*dz with NO fma contraction
#define STEPV(i) { \
    float dx = __fsub_rn(px##i, cx); \
    float dy = __fsub_rn(py##i, cy); \
    float dz = __fsub_rn(pz##i, cz); \
    float d2 = __fadd_rn(__fadd_rn(__fmul_rn(dx, dx), __fmul_rn(dy, dy)), \
                         __fmul_rn(dz, dz)); \
    float nd = fminf(dd##i, d2); dd##i = nd; \
    bool tk = nd > bv;  /* strict > : lowest local index wins ties */ \
    bv = tk ? nd : bv; \
    bl = tk ? (i) : bl; }
    RPT4(STEPV)
#undef STEPV
    int bi = (blk << 11) + (bl << 9) + t;   // global point index

    // wave argmax via DPP (VALU pipe); result valid in lane 63
    amax_dpp<0x121, 0xf>(bv, bi);       // row_ror:1
    amax_dpp<0x122, 0xf>(bv, bi);       // row_ror:2
    amax_dpp<0x124, 0xf>(bv, bi);       // row_ror:4
    amax_dpp<0x128, 0xf>(bv, bi);       // row_ror:8  -> row maxima
    amax_dpp<0x142, 0xa>(bv, bi);       // row_bcast15 -> rows 1,3
    amax_dpp<0x143, 0xc>(bv, bi);       // row_bcast31 -> lane63 has full wave

    const int par = it & 1;
    if (lane == 63) { s_wv[par][w] = bv; s_wi[par][w] = bi; }
    __syncthreads();

    float gv = s_wv[par][lane & 7];     // same-address broadcast: no conflicts
    int   gi = s_wi[par][lane & 7];
    amax_dpp<0x121, 0xf>(gv, gi);       // combine 8 wave results (period-8)
    amax_dpp<0x122, 0xf>(gv, gi);
    amax_dpp<0x124, 0xf>(gv, gi);

    if (t == 0) {
      unsigned long long key =
          ((unsigned long long)(it + 1) << 46)
        | ((unsigned long long)__float_as_uint(gv) << 14)
        | (unsigned long long)(16383 - gi);
      __hip_atomic_fetch_max(&skey[b * 2 + par], key,
                             __ATOMIC_RELAXED, __HIP_MEMORY_SCOPE_AGENT);
      __hip_atomic_fetch_add(&scnt[b], 1u,
                             __ATOMIC_RELEASE, __HIP_MEMORY_SCOPE_AGENT);
      const unsigned int target = (unsigned int)FPS_KB * (unsigned int)(it + 1);
      while (__hip_atomic_load(&scnt[b], __ATOMIC_ACQUIRE,
                               __HIP_MEMORY_SCOPE_AGENT) < target)
        __builtin_amdgcn_s_sleep(1);
      unsigned long long kk =
          __hip_atomic_load(&skey[b * 2 + par], __ATOMIC_RELAXED,
                            __HIP_MEMORY_SCOPE_AGENT);
      s_far = 16383 - (int)(kk & 0x3FFFull);
    }
    __syncthreads();

    int far = __builtin_amdgcn_readfirstlane(s_far);
    cx = base[far * 3 + 0];             // uniform centroid load (L2-resident)
    cy = base[far * 3 + 1];
    cz = base[far * 3 + 2];
  }
}

// ---------------------------------------------------------------------------
// Fallback single-block FPS (R3 version, verified) for tiny workspaces.
// ---------------------------------------------------------------------------
__global__ void __launch_bounds__(1024)
fps_single(const float* __restrict__ xyz, float* __restrict__ out_newxyz)
{
  __shared__ float2 pxy[NPTS];        // 128 KB: (x,y) per point
  __shared__ float  s_wv[2][16];
  __shared__ int    s_wi[2][16];

  const int b = blockIdx.x;
  const float* base = xyz + (size_t)b * NPTS * 3;
  const int t = threadIdx.x;
  const int lane = t & 63, w = t >> 6;

#define DECLV(i) float pz##i, dd##i;
  RPT16(DECLV)
#undef DECLV
#define LOADV(i) { const int idx = ((i) << 10) + t; \
                   const float* p = base + (size_t)idx * 3; \
                   pxy[idx] = make_float2(p[0], p[1]); \
                   pz##i = p[2]; dd##i = 1e10f; }
  RPT16(LOADV)
#undef LOADV

  float cx = base[0], cy = base[1], cz = base[2];

  for (int it = 0; it < NPOINT; ++it) {
    if (t == 0) {
      int o = (b * NPOINT + it) * 3;
      out_newxyz[o + 0] = cx;
      out_newxyz[o + 1] = cy;
      out_newxyz[o + 2] = cz;
    }
    float bv = -1.0f; int bl = 0;
#define STEPV(i) { \
    float2 q = pxy[((i) << 10) + t]; \
    float dx = __fsub_rn(q.x, cx); \
    float dy = __fsub_rn(q.y, cy); \
    float dz = __fsub_rn(pz##i, cz); \
    float d2 = __fadd_rn(__fadd_rn(__fmul_rn(dx, dx), __fmul_rn(dy, dy)), \
                         __fmul_rn(dz, dz)); \
    float nd = fminf(dd##i, d2); dd##i = nd; \
    bool tk = nd > bv; \
    bv = tk ? nd : bv; \
    bl = tk ? (i) : bl; }
    RPT16(STEPV)
#undef STEPV
    int bi = (bl << 10) + t;

    amax_dpp<0x121, 0xf>(bv, bi);
    amax_dpp<0x122, 0xf>(bv, bi);
    amax_dpp<0x124, 0xf>(bv, bi);
    amax_dpp<0x128, 0xf>(bv, bi);
    amax_dpp<0x142, 0xa>(bv, bi);
    amax_dpp<0x143, 0xc>(bv, bi);

    const int par = it & 1;
    if (lane == 63) { s_wv[par][w] = bv; s_wi[par][w] = bi; }
    __syncthreads();

    float gv = s_wv[par][lane & 15];
    int   gi = s_wi[par][lane & 15];
    amax_dpp<0x121, 0xf>(gv, gi);
    amax_dpp<0x122, 0xf>(gv, gi);
    amax_dpp<0x124, 0xf>(gv, gi);
    amax_dpp<0x128, 0xf>(gv, gi);

    int far = __builtin_amdgcn_readfirstlane(gi);
    cx = base[far * 3 + 0];
    cy = base[far * 3 + 1];
    cz = base[far * 3 + 2];
  }
}

// ---------------------------------------------------------------------------
// features (B,64,N) -> featsT (B,N,64) so per-neighbor gathers are contiguous.
// ---------------------------------------------------------------------------
__global__ __launch_bounds__(256) void transpose_kernel(
    const float* __restrict__ f, float* __restrict__ ft)
{
  __shared__ float tile[64][65];
  int b  = blockIdx.x >> 8;
  int n0 = (blockIdx.x & 255) << 6;
  for (int v = threadIdx.x; v < 64 * 64; v += 256) {
    int c = v >> 6, j = v & 63;
    tile[c][j] = f[((size_t)(b * 64 + c)) * NPTS + n0 + j];
  }
  __syncthreads();
  for (int v = threadIdx.x; v < 64 * 64; v += 256) {
    int j = v >> 6, c = v & 63;
    ft[((size_t)(b * NPTS + n0 + j)) * 64 + c] = tile[c][j];
  }
}

// ---------------------------------------------------------------------------
// Fused ball-query + gather + 3-layer MLP + max-pool. (unchanged this round)
// Block = 1024 threads, 8 centers/block, grid = 512.
// ---------------------------------------------------------------------------
__global__ __launch_bounds__(1024) void mlp_kernel(
    const float* __restrict__ xyz,
    const float* __restrict__ feats,      // (B,64,N)
    const float* __restrict__ featsT,     // (B,N,64) or null
    const float* __restrict__ nx,         // new_xyz = d_out base (B,1024,3)
    const float* __restrict__ W1, const float* __restrict__ s1, const float* __restrict__ b1,
    const float* __restrict__ W2, const float* __restrict__ s2, const float* __restrict__ b2,
    const float* __restrict__ W3, const float* __restrict__ s3, const float* __restrict__ b3,
    float* __restrict__ outF)             // d_out + 12288, (B,128,1024)
{
  __shared__ float W1t[CIN * 64];     // [i][o]
  __shared__ float W2t[64 * 64];      // [i][o]
  __shared__ float sb[512];           // s1 b1 s2 b2 s3 b3
  __shared__ float xs[CIN * 34];      // [c][k], pad 34 (2-way = free)
  __shared__ float h1[64 * 34];
  __shared__ float h2[64 * 34];
  __shared__ int   hm[128];
  __shared__ int   lid8[8][NSAMPLE];

  const int tid = threadIdx.x;
  const int lane = tid & 63, w = tid >> 6;

  for (int v = tid; v < CIN * 64; v += 1024) {
    int o = v / CIN, i = v - o * CIN;
    W1t[i * 64 + o] = W1[v];
  }
  for (int v = tid; v < 64 * 64; v += 1024) {
    int o = v >> 6, i = v & 63;
    W2t[i * 64 + o] = W2[v];
  }
  if (tid < 64)       sb[tid]       = s1[tid];
  else if (tid < 128) sb[tid]       = b1[tid - 64];
  else if (tid < 192) sb[tid]       = s2[tid - 128];
  else if (tid < 256) sb[tid]       = b2[tid - 192];
  else if (tid < 384) sb[tid]       = s3[tid - 256];
  else if (tid < 512) sb[tid]       = b3[tid - 384];

  // ---- Phase 0: ball query, one wave per center ----
  if (w < 8) {
    int g = (blockIdx.x << 3) + w;
    int b = g >> 10;
    const float* base = xyz + (size_t)b * NPTS * 3;
    float cx = nx[g * 3 + 0], cy = nx[g * 3 + 1], cz = nx[g * 3 + 2];
    int cnt = 0, fidx = -1;
    for (int c0 = 0; c0 < NPTS && cnt < NSAMPLE; c0 += 64) {
      int i = c0 + lane;
      float dx = __fsub_rn(base[i * 3 + 0], cx);
      float dy = __fsub_rn(base[i * 3 + 1], cy);
      float dz = __fsub_rn(base[i * 3 + 2], cz);
      float d2 = __fadd_rn(__fadd_rn(__fmul_rn(dx, dx), __fmul_rn(dy, dy)),
                           __fmul_rn(dz, dz));
      bool pred = d2 < R2f;
      unsigned long long mk = __ballot(pred);
      if (pred) {
        int rank = cnt + __popcll(mk & ((1ull << lane) - 1ull));
        if (rank < NSAMPLE) lid8[w][rank] = i;
        if (rank == 0) fidx = i;
      }
      cnt += __popcll(mk);
    }
#pragma unroll
    for (int off = 32; off >= 1; off >>= 1) {
      int o = __shfl_xor(fidx, off);
      fidx = o > fidx ? o : fidx;
    }
    if (lane >= cnt && lane < NSAMPLE) lid8[w][lane] = fidx;
  }
  __syncthreads();

  // ---- per-center MLP ----
  for (int ci = 0; ci < 8; ++ci) {
    int g = (blockIdx.x << 3) + ci;
    int b = g >> 10, m = g & 1023;

    // gather xs[c][k]  (+ init hm)
    {
      int k = tid >> 5, c0 = tid & 31;
      int id = lid8[ci][k];
      for (int c = c0; c < CIN; c += 32) {
        float val;
        if (c < 3)
          val = __fsub_rn(xyz[((size_t)b * NPTS + id) * 3 + c], nx[g * 3 + c]);
        else if (featsT)
          val = featsT[((size_t)b * NPTS + id) * 64 + (c - 3)];
        else
          val = feats[((size_t)(b * 64 + (c - 3))) * NPTS + id];
        xs[c * 34 + k] = val;
      }
      if (tid < 128) hm[tid] = 0;
    }
    __syncthreads();

    // L1: 67 -> 64
    {
      int oc = tid & 63, k0 = (tid >> 6) << 1;
      float a0 = 0.f, a1 = 0.f;
#pragma unroll 4
      for (int i = 0; i < CIN; ++i) {
        float ww = W1t[i * 64 + oc];
        a0 = fmaf(ww, xs[i * 34 + k0], a0);
        a1 = fmaf(ww, xs[i * 34 + k0 + 1], a1);
      }
      float s = sb[oc], bb = sb[64 + oc];
      h1[oc * 34 + k0]     = fmaxf(fmaf(a0, s, bb), 0.f);
      h1[oc * 34 + k0 + 1] = fmaxf(fmaf(a1, s, bb), 0.f);
    }
    __syncthreads();

    // L2: 64 -> 64
    {
      int oc = tid & 63, k0 = (tid >> 6) << 1;
      float a0 = 0.f, a1 = 0.f;
#pragma unroll 4
      for (int i = 0; i < 64; ++i) {
        float ww = W2t[i * 64 + oc];
        a0 = fmaf(ww, h1[i * 34 + k0], a0);
        a1 = fmaf(ww, h1[i * 34 + k0 + 1], a1);
      }
      float s = sb[128 + oc], bb = sb[192 + oc];
      h2[oc * 34 + k0]     = fmaxf(fmaf(a0, s, bb), 0.f);
      h2[oc * 34 + k0 + 1] = fmaxf(fmaf(a1, s, bb), 0.f);
    }
    __syncthreads();

    // L3: 64 -> 128, fused max over k
    {
      int oc = tid & 127, k0 = (tid >> 7) << 2;
      const float4* W3v = reinterpret_cast<const float4*>(W3);
      float a0 = 0.f, a1 = 0.f, a2 = 0.f, a3 = 0.f;
#pragma unroll 4
      for (int i4 = 0; i4 < 16; ++i4) {
        float4 wv = W3v[oc * 16 + i4];
        const float* hr = &h2[(i4 * 4) * 34 + k0];
        a0 = fmaf(wv.x, hr[0], a0); a1 = fmaf(wv.x, hr[1], a1);
        a2 = fmaf(wv.x, hr[2], a2); a3 = fmaf(wv.x, hr[3], a3);
        hr += 34;
        a0 = fmaf(wv.y, hr[0], a0); a1 = fmaf(wv.y, hr[1], a1);
        a2 = fmaf(wv.y, hr[2], a2); a3 = fmaf(wv.y, hr[3], a3);
        hr += 34;
        a0 = fmaf(wv.z, hr[0], a0); a1 = fmaf(wv.z, hr[1], a1);
        a2 = fmaf(wv.z, hr[2], a2); a3 = fmaf(wv.z, hr[3], a3);
        hr += 34;
        a0 = fmaf(wv.w, hr[0], a0); a1 = fmaf(wv.w, hr[1], a1);
        a2 = fmaf(wv.w, hr[2], a2); a3 = fmaf(wv.w, hr[3], a3);
      }
      float s = sb[256 + oc], bb = sb[384 + oc];
      float v0 = fmaxf(fmaf(a0, s, bb), 0.f);
      float v1 = fmaxf(fmaf(a1, s, bb), 0.f);
      float v2 = fmaxf(fmaf(a2, s, bb), 0.f);
      float v3 = fmaxf(fmaf(a3, s, bb), 0.f);
      float mv = fmaxf(fmaxf(v0, v1), fmaxf(v2, v3));
      atomicMax(&hm[oc], __float_as_int(mv));   // values >= 0: int order == float order
    }
    __syncthreads();

    if (tid < 128)
      outF[(((size_t)b * 128 + tid) << 10) + m] = __int_as_float(hm[tid]);
    __syncthreads();
  }
}

// ---------------------------------------------------------------------------
extern "C" void kernel_launch(void* const* d_in, const int* in_sizes, int n_in,
                              void* d_out, int out_size, void* d_ws, size_t ws_size,
                              hipStream_t stream)
{
  if (n_in < 11) return;
  const float* xyz   = (const float*)d_in[0];
  const float* feats = (const float*)d_in[1];
  const float* W1 = (const float*)d_in[2];
  const float* s1 = (const float*)d_in[3];
  const float* b1 = (const float*)d_in[4];
  const float* W2 = (const float*)d_in[5];
  const float* s2 = (const float*)d_in[6];
  const float* b2 = (const float*)d_in[7];
  const float* W3 = (const float*)d_in[8];
  const float* s3 = (const float*)d_in[9];
  const float* b3 = (const float*)d_in[10];
  float* out = (float*)d_out;

  // workspace layout: [0,256) FPS sync region; featsT after.
  const size_t SYNC_BYTES = 256;
  size_t needT = (size_t)BATCH * NPTS * 64 * sizeof(float);
  float* featsT = nullptr;
  if (ws_size >= SYNC_BYTES + needT)
    featsT = (float*)((char*)d_ws + SYNC_BYTES);

  if (ws_size >= SYNC_BYTES) {
    // zero sync region each launch (graph-captured, re-runs per replay)
    hipMemsetAsync(d_ws, 0, SYNC_BYTES, stream);
    unsigned long long* skey = (unsigned long long*)d_ws;      // [BATCH][2]
    unsigned int* scnt = (unsigned int*)((char*)d_ws + 64);    // [BATCH]
    fps_multi<<<BATCH * FPS_KB, FPS_T, 0, stream>>>(xyz, out, skey, scnt);
  } else {
    fps_single<<<BATCH, 1024, 0, stream>>>(xyz, out);
  }

  if (featsT) transpose_kernel<<<BATCH * 256, 256, 0, stream>>>(feats, featsT);
  mlp_kernel<<<512, 1024, 0, stream>>>(xyz, feats, featsT, out,
                                       W1, s1, b1, W2, s2, b2, W3, s3, b3,
                                       out + BATCH * NPOINT * 3);
}

// Round 5
// 2482.552 us; speedup vs baseline: 1.4580x; 1.4580x over previous
//
#include <hip/hip_runtime.h>
#include <cstdint>
#include <cstddef>

#define BATCH   4
#define NPTS    16384
#define NPOINT  1024
#define NSAMPLE 32
#define CIN     67          // 3 + 64 feature channels
#define R2f     0.04f       // (float)(0.2*0.2)

// ---- multi-block FPS geometry ----
#define FPS_KB  8           // blocks per batch
#define FPS_T   512         // threads per block (8 waves)
#define FPS_P   4           // 16384 / (FPS_KB*FPS_T) points per thread
#define SLOT_STRIDE 16      // u64s per slot = 128 B (own cacheline per block)
#define SYNC_BYTES  (BATCH * 2 * FPS_KB * SLOT_STRIDE * 8)   // 8 KB

#define RPT4(M)  M(0)M(1)M(2)M(3)
#define RPT16(M) M(0)M(1)M(2)M(3)M(4)M(5)M(6)M(7)M(8)M(9)M(10)M(11)M(12)M(13)M(14)M(15)

// ---------------------------------------------------------------------------
// DPP-based argmax combine: max value, tie -> lowest index. VALU-pipe only.
// ---------------------------------------------------------------------------
template <int CTRL, int RMASK>
__device__ __forceinline__ void amax_dpp(float& v, int& i) {
  int nv = __builtin_amdgcn_update_dpp(__float_as_int(v), __float_as_int(v),
                                       CTRL, RMASK, 0xf, false);
  int ni = __builtin_amdgcn_update_dpp(i, i, CTRL, RMASK, 0xf, false);
  float fv = __int_as_float(nv);
  bool tk = (fv > v) || (fv == v && ni < i);
  v = tk ? fv : v;
  i = tk ? ni : i;
}

// ---------------------------------------------------------------------------
// Multi-block FPS, RMW-free sync. R4 post-mortem: the atomicMax+fetch_add
// barrier serialized 64 same-cacheline RMWs/iter across XCDs (~3.6 us/iter;
// VALUBusy = 12% of the 32-CU ceiling -> blocks mostly waited). This round:
// zero atomic RMWs. Each block PUBLISHES its partial as one 64-bit key
//   key = (it+1)<<46 | dd_bits<<14 | (16383-idx)
// with a relaxed agent-scope STORE into its own 128B-strided slot; every
// block's wave-0 lanes 0..7 poll the 8 slots (tag==it+1; payload rides in
// the same word -> no fences), then an 8-lane shfl u64-max yields the
// winner. Stale keys lose via the tag; ping-pong by it&1 protects laggard
// readers (a block reaches it+2 only after all posted it+1, which required
// reading it). Tie-break: max(16383-idx) => lowest index, matching ref.
// 32 blocks <= 256 CUs: co-resident, no deadlock. Slots zeroed per launch.
// ---------------------------------------------------------------------------
__global__ void __launch_bounds__(FPS_T)
fps_multi(const float* __restrict__ xyz, float* __restrict__ out_newxyz,
          unsigned long long* __restrict__ slots)  // [BATCH][2][8] stride 16
{
  const int b   = blockIdx.x >> 3;                 // batch
  const int blk = blockIdx.x & 7;                  // block within batch
  const float* base = xyz + (size_t)b * NPTS * 3;
  const int t = threadIdx.x;
  const int lane = t & 63, w = t >> 6;             // w in 0..7

  // this block's chunk: global idx = (blk<<11) + (i<<9) + t
#define DECLV(i) float px##i, py##i, pz##i, dd##i;
  RPT4(DECLV)
#undef DECLV
#define LOADV(i) { const float* p = base + (size_t)((blk << 11) + ((i) << 9) + t) * 3; \
                   px##i = p[0]; py##i = p[1]; pz##i = p[2]; dd##i = 1e10f; }
  RPT4(LOADV)
#undef LOADV

  __shared__ float s_wv[2][8];
  __shared__ int   s_wi[2][8];
  __shared__ int   s_far;

  float cx = base[0], cy = base[1], cz = base[2];

  for (int it = 0; it < NPOINT; ++it) {
    if (blk == 0 && t == 0) {           // record centroid (pre-update far)
      int o = (b * NPOINT + it) * 3;
      out_newxyz[o + 0] = cx;
      out_newxyz[o + 1] = cy;
      out_newxyz[o + 2] = cz;
    }
    float bv = -1.0f; int bl = 0;
    // exactness: keep XLA's (dx*dx + dy*dy) + dz*dz with NO fma contraction
#define STEPV(i) { \
    float dx = __fsub_rn(px##i, cx); \
    float dy = __fsub_rn(py##i, cy); \
    float dz = __fsub_rn(pz##i, cz); \
    float d2 = __fadd_rn(__fadd_rn(__fmul_rn(dx, dx), __fmul_rn(dy, dy)), \
                         __fmul_rn(dz, dz)); \
    float nd = fminf(dd##i, d2); dd##i = nd; \
    bool tk = nd > bv;  /* strict > : lowest local index wins ties */ \
    bv = tk ? nd : bv; \
    bl = tk ? (i) : bl; }
    RPT4(STEPV)
#undef STEPV
    int bi = (blk << 11) + (bl << 9) + t;   // global point index

    // wave argmax via DPP (VALU pipe); result valid in lane 63
    amax_dpp<0x121, 0xf>(bv, bi);       // row_ror:1
    amax_dpp<0x122, 0xf>(bv, bi);       // row_ror:2
    amax_dpp<0x124, 0xf>(bv, bi);       // row_ror:4
    amax_dpp<0x128, 0xf>(bv, bi);       // row_ror:8  -> row maxima
    amax_dpp<0x142, 0xa>(bv, bi);       // row_bcast15 -> rows 1,3
    amax_dpp<0x143, 0xc>(bv, bi);       // row_bcast31 -> lane63 has full wave

    const int par = it & 1;
    if (lane == 63) { s_wv[par][w] = bv; s_wi[par][w] = bi; }
    __syncthreads();

    if (w == 0) {                       // wave 0 handles publish+combine
      float gv = s_wv[par][lane & 7];   // same-address broadcast
      int   gi = s_wi[par][lane & 7];
      amax_dpp<0x121, 0xf>(gv, gi);     // combine 8 wave results (period-8)
      amax_dpp<0x122, 0xf>(gv, gi);
      amax_dpp<0x124, 0xf>(gv, gi);

      unsigned long long* sb_ = slots + ((size_t)(b * 2 + par) * FPS_KB) * SLOT_STRIDE;
      if (lane == 0) {
        unsigned long long key =
            ((unsigned long long)(it + 1) << 46)
          | ((unsigned long long)__float_as_uint(gv) << 14)
          | (unsigned long long)(16383 - gi);
        __hip_atomic_store(&sb_[blk * SLOT_STRIDE], key,
                           __ATOMIC_RELAXED, __HIP_MEMORY_SCOPE_AGENT);
      }
      unsigned long long kk = 0;
      if (lane < 8) {                   // each lane polls one slot
        const unsigned long long tag = (unsigned long long)(it + 1);
        do {
          kk = __hip_atomic_load(&sb_[lane * SLOT_STRIDE],
                                 __ATOMIC_RELAXED, __HIP_MEMORY_SCOPE_AGENT);
        } while ((kk >> 46) != tag);
      }
#pragma unroll
      for (int off = 1; off < 8; off <<= 1) {
        unsigned long long o = __shfl_xor(kk, off);
        kk = o > kk ? o : kk;
      }
      if (lane == 0) s_far = 16383 - (int)(kk & 0x3FFFull);
    }
    __syncthreads();

    int far = __builtin_amdgcn_readfirstlane(s_far);
    cx = base[far * 3 + 0];             // uniform centroid load (L2-resident)
    cy = base[far * 3 + 1];
    cz = base[far * 3 + 2];
  }
}

// ---------------------------------------------------------------------------
// Fallback single-block FPS (R3 version, verified) for tiny workspaces.
// ---------------------------------------------------------------------------
__global__ void __launch_bounds__(1024)
fps_single(const float* __restrict__ xyz, float* __restrict__ out_newxyz)
{
  __shared__ float2 pxy[NPTS];        // 128 KB: (x,y) per point
  __shared__ float  s_wv[2][16];
  __shared__ int    s_wi[2][16];

  const int b = blockIdx.x;
  const float* base = xyz + (size_t)b * NPTS * 3;
  const int t = threadIdx.x;
  const int lane = t & 63, w = t >> 6;

#define DECLV(i) float pz##i, dd##i;
  RPT16(DECLV)
#undef DECLV
#define LOADV(i) { const int idx = ((i) << 10) + t; \
                   const float* p = base + (size_t)idx * 3; \
                   pxy[idx] = make_float2(p[0], p[1]); \
                   pz##i = p[2]; dd##i = 1e10f; }
  RPT16(LOADV)
#undef LOADV

  float cx = base[0], cy = base[1], cz = base[2];

  for (int it = 0; it < NPOINT; ++it) {
    if (t == 0) {
      int o = (b * NPOINT + it) * 3;
      out_newxyz[o + 0] = cx;
      out_newxyz[o + 1] = cy;
      out_newxyz[o + 2] = cz;
    }
    float bv = -1.0f; int bl = 0;
#define STEPV(i) { \
    float2 q = pxy[((i) << 10) + t]; \
    float dx = __fsub_rn(q.x, cx); \
    float dy = __fsub_rn(q.y, cy); \
    float dz = __fsub_rn(pz##i, cz); \
    float d2 = __fadd_rn(__fadd_rn(__fmul_rn(dx, dx), __fmul_rn(dy, dy)), \
                         __fmul_rn(dz, dz)); \
    float nd = fminf(dd##i, d2); dd##i = nd; \
    bool tk = nd > bv; \
    bv = tk ? nd : bv; \
    bl = tk ? (i) : bl; }
    RPT16(STEPV)
#undef STEPV
    int bi = (bl << 10) + t;

    amax_dpp<0x121, 0xf>(bv, bi);
    amax_dpp<0x122, 0xf>(bv, bi);
    amax_dpp<0x124, 0xf>(bv, bi);
    amax_dpp<0x128, 0xf>(bv, bi);
    amax_dpp<0x142, 0xa>(bv, bi);
    amax_dpp<0x143, 0xc>(bv, bi);

    const int par = it & 1;
    if (lane == 63) { s_wv[par][w] = bv; s_wi[par][w] = bi; }
    __syncthreads();

    float gv = s_wv[par][lane & 15];
    int   gi = s_wi[par][lane & 15];
    amax_dpp<0x121, 0xf>(gv, gi);
    amax_dpp<0x122, 0xf>(gv, gi);
    amax_dpp<0x124, 0xf>(gv, gi);
    amax_dpp<0x128, 0xf>(gv, gi);

    int far = __builtin_amdgcn_readfirstlane(gi);
    cx = base[far * 3 + 0];
    cy = base[far * 3 + 1];
    cz = base[far * 3 + 2];
  }
}

// ---------------------------------------------------------------------------
// features (B,64,N) -> featsT (B,N,64) so per-neighbor gathers are contiguous.
// ---------------------------------------------------------------------------
__global__ __launch_bounds__(256) void transpose_kernel(
    const float* __restrict__ f, float* __restrict__ ft)
{
  __shared__ float tile[64][65];
  int b  = blockIdx.x >> 8;
  int n0 = (blockIdx.x & 255) << 6;
  for (int v = threadIdx.x; v < 64 * 64; v += 256) {
    int c = v >> 6, j = v & 63;
    tile[c][j] = f[((size_t)(b * 64 + c)) * NPTS + n0 + j];
  }
  __syncthreads();
  for (int v = threadIdx.x; v < 64 * 64; v += 256) {
    int j = v >> 6, c = v & 63;
    ft[((size_t)(b * NPTS + n0 + j)) * 64 + c] = tile[c][j];
  }
}

// ---------------------------------------------------------------------------
// Fused ball-query + gather + 3-layer MLP + max-pool. (unchanged this round)
// Block = 1024 threads, 8 centers/block, grid = 512.
// ---------------------------------------------------------------------------
__global__ __launch_bounds__(1024) void mlp_kernel(
    const float* __restrict__ xyz,
    const float* __restrict__ feats,      // (B,64,N)
    const float* __restrict__ featsT,     // (B,N,64) or null
    const float* __restrict__ nx,         // new_xyz = d_out base (B,1024,3)
    const float* __restrict__ W1, const float* __restrict__ s1, const float* __restrict__ b1,
    const float* __restrict__ W2, const float* __restrict__ s2, const float* __restrict__ b2,
    const float* __restrict__ W3, const float* __restrict__ s3, const float* __restrict__ b3,
    float* __restrict__ outF)             // d_out + 12288, (B,128,1024)
{
  __shared__ float W1t[CIN * 64];     // [i][o]
  __shared__ float W2t[64 * 64];      // [i][o]
  __shared__ float sb[512];           // s1 b1 s2 b2 s3 b3
  __shared__ float xs[CIN * 34];      // [c][k], pad 34 (2-way = free)
  __shared__ float h1[64 * 34];
  __shared__ float h2[64 * 34];
  __shared__ int   hm[128];
  __shared__ int   lid8[8][NSAMPLE];

  const int tid = threadIdx.x;
  const int lane = tid & 63, w = tid >> 6;

  for (int v = tid; v < CIN * 64; v += 1024) {
    int o = v / CIN, i = v - o * CIN;
    W1t[i * 64 + o] = W1[v];
  }
  for (int v = tid; v < 64 * 64; v += 1024) {
    int o = v >> 6, i = v & 63;
    W2t[i * 64 + o] = W2[v];
  }
  if (tid < 64)       sb[tid]       = s1[tid];
  else if (tid < 128) sb[tid]       = b1[tid - 64];
  else if (tid < 192) sb[tid]       = s2[tid - 128];
  else if (tid < 256) sb[tid]       = b2[tid - 192];
  else if (tid < 384) sb[tid]       = s3[tid - 256];
  else if (tid < 512) sb[tid]       = b3[tid - 384];

  // ---- Phase 0: ball query, one wave per center ----
  if (w < 8) {
    int g = (blockIdx.x << 3) + w;
    int b = g >> 10;
    const float* base = xyz + (size_t)b * NPTS * 3;
    float cx = nx[g * 3 + 0], cy = nx[g * 3 + 1], cz = nx[g * 3 + 2];
    int cnt = 0, fidx = -1;
    for (int c0 = 0; c0 < NPTS && cnt < NSAMPLE; c0 += 64) {
      int i = c0 + lane;
      float dx = __fsub_rn(base[i * 3 + 0], cx);
      float dy = __fsub_rn(base[i * 3 + 1], cy);
      float dz = __fsub_rn(base[i * 3 + 2], cz);
      float d2 = __fadd_rn(__fadd_rn(__fmul_rn(dx, dx), __fmul_rn(dy, dy)),
                           __fmul_rn(dz, dz));
      bool pred = d2 < R2f;
      unsigned long long mk = __ballot(pred);
      if (pred) {
        int rank = cnt + __popcll(mk & ((1ull << lane) - 1ull));
        if (rank < NSAMPLE) lid8[w][rank] = i;
        if (rank == 0) fidx = i;
      }
      cnt += __popcll(mk);
    }
#pragma unroll
    for (int off = 32; off >= 1; off >>= 1) {
      int o = __shfl_xor(fidx, off);
      fidx = o > fidx ? o : fidx;
    }
    if (lane >= cnt && lane < NSAMPLE) lid8[w][lane] = fidx;
  }
  __syncthreads();

  // ---- per-center MLP ----
  for (int ci = 0; ci < 8; ++ci) {
    int g = (blockIdx.x << 3) + ci;
    int b = g >> 10, m = g & 1023;

    // gather xs[c][k]  (+ init hm)
    {
      int k = tid >> 5, c0 = tid & 31;
      int id = lid8[ci][k];
      for (int c = c0; c < CIN; c += 32) {
        float val;
        if (c < 3)
          val = __fsub_rn(xyz[((size_t)b * NPTS + id) * 3 + c], nx[g * 3 + c]);
        else if (featsT)
          val = featsT[((size_t)b * NPTS + id) * 64 + (c - 3)];
        else
          val = feats[((size_t)(b * 64 + (c - 3))) * NPTS + id];
        xs[c * 34 + k] = val;
      }
      if (tid < 128) hm[tid] = 0;
    }
    __syncthreads();

    // L1: 67 -> 64
    {
      int oc = tid & 63, k0 = (tid >> 6) << 1;
      float a0 = 0.f, a1 = 0.f;
#pragma unroll 4
      for (int i = 0; i < CIN; ++i) {
        float ww = W1t[i * 64 + oc];
        a0 = fmaf(ww, xs[i * 34 + k0], a0);
        a1 = fmaf(ww, xs[i * 34 + k0 + 1], a1);
      }
      float s = sb[oc], bb = sb[64 + oc];
      h1[oc * 34 + k0]     = fmaxf(fmaf(a0, s, bb), 0.f);
      h1[oc * 34 + k0 + 1] = fmaxf(fmaf(a1, s, bb), 0.f);
    }
    __syncthreads();

    // L2: 64 -> 64
    {
      int oc = tid & 63, k0 = (tid >> 6) << 1;
      float a0 = 0.f, a1 = 0.f;
#pragma unroll 4
      for (int i = 0; i < 64; ++i) {
        float ww = W2t[i * 64 + oc];
        a0 = fmaf(ww, h1[i * 34 + k0], a0);
        a1 = fmaf(ww, h1[i * 34 + k0 + 1], a1);
      }
      float s = sb[128 + oc], bb = sb[192 + oc];
      h2[oc * 34 + k0]     = fmaxf(fmaf(a0, s, bb), 0.f);
      h2[oc * 34 + k0 + 1] = fmaxf(fmaf(a1, s, bb), 0.f);
    }
    __syncthreads();

    // L3: 64 -> 128, fused max over k
    {
      int oc = tid & 127, k0 = (tid >> 7) << 2;
      const float4* W3v = reinterpret_cast<const float4*>(W3);
      float a0 = 0.f, a1 = 0.f, a2 = 0.f, a3 = 0.f;
#pragma unroll 4
      for (int i4 = 0; i4 < 16; ++i4) {
        float4 wv = W3v[oc * 16 + i4];
        const float* hr = &h2[(i4 * 4) * 34 + k0];
        a0 = fmaf(wv.x, hr[0], a0); a1 = fmaf(wv.x, hr[1], a1);
        a2 = fmaf(wv.x, hr[2], a2); a3 = fmaf(wv.x, hr[3], a3);
        hr += 34;
        a0 = fmaf(wv.y, hr[0], a0); a1 = fmaf(wv.y, hr[1], a1);
        a2 = fmaf(wv.y, hr[2], a2); a3 = fmaf(wv.y, hr[3], a3);
        hr += 34;
        a0 = fmaf(wv.z, hr[0], a0); a1 = fmaf(wv.z, hr[1], a1);
        a2 = fmaf(wv.z, hr[2], a2); a3 = fmaf(wv.z, hr[3], a3);
        hr += 34;
        a0 = fmaf(wv.w, hr[0], a0); a1 = fmaf(wv.w, hr[1], a1);
        a2 = fmaf(wv.w, hr[2], a2); a3 = fmaf(wv.w, hr[3], a3);
      }
      float s = sb[256 + oc], bb = sb[384 + oc];
      float v0 = fmaxf(fmaf(a0, s, bb), 0.f);
      float v1 = fmaxf(fmaf(a1, s, bb), 0.f);
      float v2 = fmaxf(fmaf(a2, s, bb), 0.f);
      float v3 = fmaxf(fmaf(a3, s, bb), 0.f);
      float mv = fmaxf(fmaxf(v0, v1), fmaxf(v2, v3));
      atomicMax(&hm[oc], __float_as_int(mv));   // values >= 0: int order == float order
    }
    __syncthreads();

    if (tid < 128)
      outF[(((size_t)b * 128 + tid) << 10) + m] = __int_as_float(hm[tid]);
    __syncthreads();
  }
}

// ---------------------------------------------------------------------------
extern "C" void kernel_launch(void* const* d_in, const int* in_sizes, int n_in,
                              void* d_out, int out_size, void* d_ws, size_t ws_size,
                              hipStream_t stream)
{
  if (n_in < 11) return;
  const float* xyz   = (const float*)d_in[0];
  const float* feats = (const float*)d_in[1];
  const float* W1 = (const float*)d_in[2];
  const float* s1 = (const float*)d_in[3];
  const float* b1 = (const float*)d_in[4];
  const float* W2 = (const float*)d_in[5];
  const float* s2 = (const float*)d_in[6];
  const float* b2 = (const float*)d_in[7];
  const float* W3 = (const float*)d_in[8];
  const float* s3 = (const float*)d_in[9];
  const float* b3 = (const float*)d_in[10];
  float* out = (float*)d_out;

  // workspace layout: [0, SYNC_BYTES) FPS slots; featsT after.
  size_t needT = (size_t)BATCH * NPTS * 64 * sizeof(float);
  float* featsT = nullptr;
  if (ws_size >= SYNC_BYTES + needT)
    featsT = (float*)((char*)d_ws + SYNC_BYTES);

  if (ws_size >= SYNC_BYTES) {
    // zero slots each launch (graph-captured, re-runs per replay)
    hipMemsetAsync(d_ws, 0, SYNC_BYTES, stream);
    fps_multi<<<BATCH * FPS_KB, FPS_T, 0, stream>>>(
        xyz, out, (unsigned long long*)d_ws);
  } else {
    fps_single<<<BATCH, 1024, 0, stream>>>(xyz, out);
  }

  if (featsT) transpose_kernel<<<BATCH * 256, 256, 0, stream>>>(feats, featsT);
  mlp_kernel<<<512, 1024, 0, stream>>>(xyz, feats, featsT, out,
                                       W1, s1, b1, W2, s2, b2, W3, s3, b3,
                                       out + BATCH * NPOINT * 3);
}

// Round 7
// 2282.820 us; speedup vs baseline: 1.5855x; 1.0875x over previous
//
#include <hip/hip_runtime.h>
#include <cstdint>
#include <cstddef>

// Exactness: prevent mul+add fusion everywhere (XLA ref uses unfused
// (dx*dx+dy*dy)+dz*dz). Explicit fmaf() calls in mlp_kernel are unaffected.
#pragma clang fp contract(off)

#define BATCH   4
#define NPTS    16384
#define NPOINT  1024
#define NSAMPLE 32
#define CIN     67          // 3 + 64 feature channels
#define R2f     0.04f       // (float)(0.2*0.2)

#define FPS_T   512         // 8 waves, one block per batch
#define FPS_PAD 34          // floats per thread-row in LDS SoA (8B-aligned, 2-way bank = free)

#define RPT16(M) M(0)M(1)M(2)M(3)M(4)M(5)M(6)M(7)M(8)M(9)M(10)M(11)M(12)M(13)M(14)M(15)

typedef float v2f __attribute__((ext_vector_type(2)));

// ---------------------------------------------------------------------------
// DPP-based argmax combine: max value, tie -> lowest index. VALU-pipe only.
// ---------------------------------------------------------------------------
template <int CTRL, int RMASK>
__device__ __forceinline__ void amax_dpp(float& v, int& i) {
  int nv = __builtin_amdgcn_update_dpp(__float_as_int(v), __float_as_int(v),
                                       CTRL, RMASK, 0xf, false);
  int ni = __builtin_amdgcn_update_dpp(i, i, CTRL, RMASK, 0xf, false);
  float fv = __int_as_float(nv);
  bool tk = (fv > v) || (fv == v && ni < i);
  v = tk ? fv : v;
  i = tk ? ni : i;
}

// ---------------------------------------------------------------------------
// Single-block FPS, packed-FP32 core. R5 post-mortem: cross-block sync costs
// ~2us/iter at ANY primitive (agent-scope ops coherence-point is L3 on the
// 8-XCD chip: R4 RMWs 3.6us, R5 store+poll 1.9us, FETCH 18.5MB of poll
// traffic) == the whole single-block iteration -> multi-block is dead.
// This round: cut single-block VALU issue. 512 thr (8 waves: per-wave fixed
// cost halves vs 1024 -- R0 1951 vs R3 2134), 32 pts/thread.
//  - LDS SoA px/py[t*34+k]: ds_read_b64 yields a POINT-PAIR {k,k+1} directly;
//    pad 34 keeps 8B alignment and 2-way bank alias (free, m136).
//  - pz,dd as 16+16 v2f regs. dd is loop-modified (cannot be remat'd -- the
//    R3-proven residency trick); pz pinned by in-loop asm so its global
//    loads cannot be sunk into the loop (R2 pathology: VGPR=48 + remat).
//  - distance core in v2f -> v_pk_add/mul_f32 (full-rate on CDNA4), per-
//    component rn rounding IDENTICAL to scalar; fp contract off (file scope).
//  - tie-break exact: pair (>=) prefers lower k; thread scan strict > keeps
//    lowest k; wave/block DPP argmax carries true global idx bi=(k<<9)+t.
// (R6: compile fix only -- the fp-contract pragma must be at file scope.)
// ---------------------------------------------------------------------------
__global__ void __launch_bounds__(FPS_T)
fps_kernel(const float* __restrict__ xyz, float* __restrict__ out_newxyz)
{
  __shared__ float px[FPS_T * FPS_PAD];   // 69632 B
  __shared__ float py[FPS_T * FPS_PAD];   // 69632 B
  __shared__ float s_wv[2][8];
  __shared__ int   s_wi[2][8];

  const int b = blockIdx.x;
  const float* base = xyz + (size_t)b * NPTS * 3;
  const int t = threadIdx.x;
  const int lane = t & 63, w = t >> 6;        // w in 0..7
  const int t34 = t * FPS_PAD;

  // init: global idx of thread t's k-th point = (k<<9) + t  (coalesced-ish)
#define INITP(j) v2f pz##j, dd##j; { \
    const float* p0 = base + (size_t)(((2*(j)) << 9) + t) * 3; \
    const float* p1 = base + (size_t)(((2*(j)+1) << 9) + t) * 3; \
    px[t34 + 2*(j)]     = p0[0];  px[t34 + 2*(j) + 1] = p1[0]; \
    py[t34 + 2*(j)]     = p0[1];  py[t34 + 2*(j) + 1] = p1[1]; \
    pz##j.x = p0[2];  pz##j.y = p1[2]; \
    dd##j.x = 1e10f;  dd##j.y = 1e10f; }
  RPT16(INITP)
#undef INITP

  float cx = base[0], cy = base[1], cz = base[2];

  for (int it = 0; it < NPOINT; ++it) {
    // pin pz/dd as loop-carried VGPR pairs: not remat-able, not sinkable
#define PINJ(j) asm volatile("" : "+v"(pz##j), "+v"(dd##j));
    RPT16(PINJ)
#undef PINJ

    if (t == 0) {                       // record centroid (pre-update far)
      int o = (b * NPOINT + it) * 3;
      out_newxyz[o + 0] = cx;
      out_newxyz[o + 1] = cy;
      out_newxyz[o + 2] = cz;
    }

    v2f cx2, cy2, cz2;
    cx2.x = cx; cx2.y = cx;
    cy2.x = cy; cy2.y = cy;
    cz2.x = cz; cz2.y = cz;

    float bv = -1.0f; int bl = 0;
    // exactness: per-component (dx*dx + dy*dy) + dz*dz, rn, NO contraction
#define STEP2(j) { \
    v2f xx = *reinterpret_cast<const v2f*>(&px[t34 + 2*(j)]); \
    v2f yy = *reinterpret_cast<const v2f*>(&py[t34 + 2*(j)]); \
    v2f dx = xx - cx2; \
    v2f dy = yy - cy2; \
    v2f dz = pz##j - cz2; \
    v2f sx = dx * dx; \
    v2f sy = dy * dy; \
    v2f sz = dz * dz; \
    v2f d2 = (sx + sy) + sz; \
    v2f nd; \
    nd.x = fminf(dd##j.x, d2.x); \
    nd.y = fminf(dd##j.y, d2.y); \
    dd##j = nd; \
    float m = fmaxf(nd.x, nd.y); \
    int kw = (nd.x >= nd.y) ? (2*(j)) : (2*(j)+1);  /* lower k wins ties */ \
    bool tk = m > bv;                               /* strict >: lowest k */ \
    bv = tk ? m : bv; \
    bl = tk ? kw : bl; }
    RPT16(STEP2)
#undef STEP2
    int bi = (bl << 9) + t;             // true global point index

    // wave argmax via DPP (VALU pipe); result valid in lane 63
    amax_dpp<0x121, 0xf>(bv, bi);       // row_ror:1
    amax_dpp<0x122, 0xf>(bv, bi);       // row_ror:2
    amax_dpp<0x124, 0xf>(bv, bi);       // row_ror:4
    amax_dpp<0x128, 0xf>(bv, bi);       // row_ror:8  -> row maxima
    amax_dpp<0x142, 0xa>(bv, bi);       // row_bcast15 -> rows 1,3
    amax_dpp<0x143, 0xc>(bv, bi);       // row_bcast31 -> lane63 has full wave

    const int par = it & 1;
    if (lane == 63) { s_wv[par][w] = bv; s_wi[par][w] = bi; }
    __syncthreads();

    float gv = s_wv[par][lane & 7];     // same-address broadcast: no conflicts
    int   gi = s_wi[par][lane & 7];
    amax_dpp<0x121, 0xf>(gv, gi);       // combine 8 wave results (period-8)
    amax_dpp<0x122, 0xf>(gv, gi);
    amax_dpp<0x124, 0xf>(gv, gi);

    int far = __builtin_amdgcn_readfirstlane(gi);
    cx = base[far * 3 + 0];             // uniform centroid load (L2-resident)
    cy = base[far * 3 + 1];
    cz = base[far * 3 + 2];
  }
}

// ---------------------------------------------------------------------------
// features (B,64,N) -> featsT (B,N,64) so per-neighbor gathers are contiguous.
// ---------------------------------------------------------------------------
__global__ __launch_bounds__(256) void transpose_kernel(
    const float* __restrict__ f, float* __restrict__ ft)
{
  __shared__ float tile[64][65];
  int b  = blockIdx.x >> 8;
  int n0 = (blockIdx.x & 255) << 6;
  for (int v = threadIdx.x; v < 64 * 64; v += 256) {
    int c = v >> 6, j = v & 63;
    tile[c][j] = f[((size_t)(b * 64 + c)) * NPTS + n0 + j];
  }
  __syncthreads();
  for (int v = threadIdx.x; v < 64 * 64; v += 256) {
    int j = v >> 6, c = v & 63;
    ft[((size_t)(b * NPTS + n0 + j)) * 64 + c] = tile[c][j];
  }
}

// ---------------------------------------------------------------------------
// Fused ball-query + gather + 3-layer MLP + max-pool. (unchanged this round)
// Block = 1024 threads, 8 centers/block, grid = 512.
// ---------------------------------------------------------------------------
__global__ __launch_bounds__(1024) void mlp_kernel(
    const float* __restrict__ xyz,
    const float* __restrict__ feats,      // (B,64,N)
    const float* __restrict__ featsT,     // (B,N,64) or null
    const float* __restrict__ nx,         // new_xyz = d_out base (B,1024,3)
    const float* __restrict__ W1, const float* __restrict__ s1, const float* __restrict__ b1,
    const float* __restrict__ W2, const float* __restrict__ s2, const float* __restrict__ b2,
    const float* __restrict__ W3, const float* __restrict__ s3, const float* __restrict__ b3,
    float* __restrict__ outF)             // d_out + 12288, (B,128,1024)
{
  __shared__ float W1t[CIN * 64];     // [i][o]
  __shared__ float W2t[64 * 64];      // [i][o]
  __shared__ float sb[512];           // s1 b1 s2 b2 s3 b3
  __shared__ float xs[CIN * 34];      // [c][k], pad 34 (2-way = free)
  __shared__ float h1[64 * 34];
  __shared__ float h2[64 * 34];
  __shared__ int   hm[128];
  __shared__ int   lid8[8][NSAMPLE];

  const int tid = threadIdx.x;
  const int lane = tid & 63, w = tid >> 6;

  for (int v = tid; v < CIN * 64; v += 1024) {
    int o = v / CIN, i = v - o * CIN;
    W1t[i * 64 + o] = W1[v];
  }
  for (int v = tid; v < 64 * 64; v += 1024) {
    int o = v >> 6, i = v & 63;
    W2t[i * 64 + o] = W2[v];
  }
  if (tid < 64)       sb[tid]       = s1[tid];
  else if (tid < 128) sb[tid]       = b1[tid - 64];
  else if (tid < 192) sb[tid]       = s2[tid - 128];
  else if (tid < 256) sb[tid]       = b2[tid - 192];
  else if (tid < 384) sb[tid]       = s3[tid - 256];
  else if (tid < 512) sb[tid]       = b3[tid - 384];

  // ---- Phase 0: ball query, one wave per center ----
  if (w < 8) {
    int g = (blockIdx.x << 3) + w;
    int b = g >> 10;
    const float* base = xyz + (size_t)b * NPTS * 3;
    float cx = nx[g * 3 + 0], cy = nx[g * 3 + 1], cz = nx[g * 3 + 2];
    int cnt = 0, fidx = -1;
    for (int c0 = 0; c0 < NPTS && cnt < NSAMPLE; c0 += 64) {
      int i = c0 + lane;
      float dx = __fsub_rn(base[i * 3 + 0], cx);
      float dy = __fsub_rn(base[i * 3 + 1], cy);
      float dz = __fsub_rn(base[i * 3 + 2], cz);
      float d2 = __fadd_rn(__fadd_rn(__fmul_rn(dx, dx), __fmul_rn(dy, dy)),
                           __fmul_rn(dz, dz));
      bool pred = d2 < R2f;
      unsigned long long mk = __ballot(pred);
      if (pred) {
        int rank = cnt + __popcll(mk & ((1ull << lane) - 1ull));
        if (rank < NSAMPLE) lid8[w][rank] = i;
        if (rank == 0) fidx = i;
      }
      cnt += __popcll(mk);
    }
#pragma unroll
    for (int off = 32; off >= 1; off >>= 1) {
      int o = __shfl_xor(fidx, off);
      fidx = o > fidx ? o : fidx;
    }
    if (lane >= cnt && lane < NSAMPLE) lid8[w][lane] = fidx;
  }
  __syncthreads();

  // ---- per-center MLP ----
  for (int ci = 0; ci < 8; ++ci) {
    int g = (blockIdx.x << 3) + ci;
    int b = g >> 10, m = g & 1023;

    // gather xs[c][k]  (+ init hm)
    {
      int k = tid >> 5, c0 = tid & 31;
      int id = lid8[ci][k];
      for (int c = c0; c < CIN; c += 32) {
        float val;
        if (c < 3)
          val = __fsub_rn(xyz[((size_t)b * NPTS + id) * 3 + c], nx[g * 3 + c]);
        else if (featsT)
          val = featsT[((size_t)b * NPTS + id) * 64 + (c - 3)];
        else
          val = feats[((size_t)(b * 64 + (c - 3))) * NPTS + id];
        xs[c * 34 + k] = val;
      }
      if (tid < 128) hm[tid] = 0;
    }
    __syncthreads();

    // L1: 67 -> 64
    {
      int oc = tid & 63, k0 = (tid >> 6) << 1;
      float a0 = 0.f, a1 = 0.f;
#pragma unroll 4
      for (int i = 0; i < CIN; ++i) {
        float ww = W1t[i * 64 + oc];
        a0 = fmaf(ww, xs[i * 34 + k0], a0);
        a1 = fmaf(ww, xs[i * 34 + k0 + 1], a1);
      }
      float s = sb[oc], bb = sb[64 + oc];
      h1[oc * 34 + k0]     = fmaxf(fmaf(a0, s, bb), 0.f);
      h1[oc * 34 + k0 + 1] = fmaxf(fmaf(a1, s, bb), 0.f);
    }
    __syncthreads();

    // L2: 64 -> 64
    {
      int oc = tid & 63, k0 = (tid >> 6) << 1;
      float a0 = 0.f, a1 = 0.f;
#pragma unroll 4
      for (int i = 0; i < 64; ++i) {
        float ww = W2t[i * 64 + oc];
        a0 = fmaf(ww, h1[i * 34 + k0], a0);
        a1 = fmaf(ww, h1[i * 34 + k0 + 1], a1);
      }
      float s = sb[128 + oc], bb = sb[192 + oc];
      h2[oc * 34 + k0]     = fmaxf(fmaf(a0, s, bb), 0.f);
      h2[oc * 34 + k0 + 1] = fmaxf(fmaf(a1, s, bb), 0.f);
    }
    __syncthreads();

    // L3: 64 -> 128, fused max over k
    {
      int oc = tid & 127, k0 = (tid >> 7) << 2;
      const float4* W3v = reinterpret_cast<const float4*>(W3);
      float a0 = 0.f, a1 = 0.f, a2 = 0.f, a3 = 0.f;
#pragma unroll 4
      for (int i4 = 0; i4 < 16; ++i4) {
        float4 wv = W3v[oc * 16 + i4];
        const float* hr = &h2[(i4 * 4) * 34 + k0];
        a0 = fmaf(wv.x, hr[0], a0); a1 = fmaf(wv.x, hr[1], a1);
        a2 = fmaf(wv.x, hr[2], a2); a3 = fmaf(wv.x, hr[3], a3);
        hr += 34;
        a0 = fmaf(wv.y, hr[0], a0); a1 = fmaf(wv.y, hr[1], a1);
        a2 = fmaf(wv.y, hr[2], a2); a3 = fmaf(wv.y, hr[3], a3);
        hr += 34;
        a0 = fmaf(wv.z, hr[0], a0); a1 = fmaf(wv.z, hr[1], a1);
        a2 = fmaf(wv.z, hr[2], a2); a3 = fmaf(wv.z, hr[3], a3);
        hr += 34;
        a0 = fmaf(wv.w, hr[0], a0); a1 = fmaf(wv.w, hr[1], a1);
        a2 = fmaf(wv.w, hr[2], a2); a3 = fmaf(wv.w, hr[3], a3);
      }
      float s = sb[256 + oc], bb = sb[384 + oc];
      float v0 = fmaxf(fmaf(a0, s, bb), 0.f);
      float v1 = fmaxf(fmaf(a1, s, bb), 0.f);
      float v2 = fmaxf(fmaf(a2, s, bb), 0.f);
      float v3 = fmaxf(fmaf(a3, s, bb), 0.f);
      float mv = fmaxf(fmaxf(v0, v1), fmaxf(v2, v3));
      atomicMax(&hm[oc], __float_as_int(mv));   // values >= 0: int order == float order
    }
    __syncthreads();

    if (tid < 128)
      outF[(((size_t)b * 128 + tid) << 10) + m] = __int_as_float(hm[tid]);
    __syncthreads();
  }
}

// ---------------------------------------------------------------------------
extern "C" void kernel_launch(void* const* d_in, const int* in_sizes, int n_in,
                              void* d_out, int out_size, void* d_ws, size_t ws_size,
                              hipStream_t stream)
{
  if (n_in < 11) return;
  const float* xyz   = (const float*)d_in[0];
  const float* feats = (const float*)d_in[1];
  const float* W1 = (const float*)d_in[2];
  const float* s1 = (const float*)d_in[3];
  const float* b1 = (const float*)d_in[4];
  const float* W2 = (const float*)d_in[5];
  const float* s2 = (const float*)d_in[6];
  const float* b2 = (const float*)d_in[7];
  const float* W3 = (const float*)d_in[8];
  const float* s3 = (const float*)d_in[9];
  const float* b3 = (const float*)d_in[10];
  float* out = (float*)d_out;

  // optional workspace: transposed features (B,N,64)
  float* featsT = nullptr;
  size_t needT = (size_t)BATCH * NPTS * 64 * sizeof(float);
  if (ws_size >= needT) featsT = (float*)d_ws;

  fps_kernel<<<BATCH, FPS_T, 0, stream>>>(xyz, out);
  if (featsT) transpose_kernel<<<BATCH * 256, 256, 0, stream>>>(feats, featsT);
  mlp_kernel<<<512, 1024, 0, stream>>>(xyz, feats, featsT, out,
                                       W1, s1, b1, W2, s2, b2, W3, s3, b3,
                                       out + BATCH * NPOINT * 3);
}